// Round 1
// baseline (297.655 us; speedup 1.0000x reference)
//
#include <hip/hip_runtime.h>
#include <stdint.h>

#define S_LEN 4096
#define DIM 256
#define BM 128
#define BN 128
#define BK 32

typedef short bf16x8 __attribute__((ext_vector_type(8)));
typedef float f32x4 __attribute__((ext_vector_type(4)));

typedef __attribute__((address_space(1))) void gv_t;
typedef __attribute__((address_space(3))) void lv_t;

__device__ __forceinline__ uint16_t f2bf(float f) {
  uint32_t u = __float_as_uint(f);
  return (uint16_t)((u + 0x7FFFu + ((u >> 16) & 1u)) >> 16);
}
__device__ __forceinline__ float bf2f(uint16_t h) {
  return __uint_as_float(((uint32_t)h) << 16);
}
__device__ __forceinline__ float tanh_fast(float x) {
  float e = __expf(2.0f * x);       // inf for large x -> returns exactly 1
  return 1.0f - 2.0f / (e + 1.0f);  // -> -1 for very negative x
}

// Stage a 128x32 bf16 tile (rows [0,128), cols [k0,k0+32) of a row-major
// [*,256] matrix) into LDS row-major [128][32] via async global->LDS, 16B/lane.
// LDS layout is exactly lane-contiguous (base + lane*16) as required.
__device__ __forceinline__ void stage_tile(const uint16_t* gbase, uint16_t* lds,
                                           int wave, int lane) {
#pragma unroll
  for (int t = 0; t < 2; ++t) {
    int r = ((wave << 1) + t) * 16 + (lane >> 2);
    int c = (lane & 3) * 8;
    const uint16_t* g = gbase + r * DIM + c;
    uint16_t* l = lds + ((wave << 1) + t) * 512;  // wave-uniform LDS base
    __builtin_amdgcn_global_load_lds((gv_t*)g, (lv_t*)l, 16, 0, 0);
  }
}

// NT-GEMM core: C[i][j] = sum_k A[i0+i,k]*B[j0+j,k], A/B bf16 row-major with
// row stride DIM=256. Block = 256 threads = 4 waves; wave (wm,wn) owns a
// 64x64 quadrant as 4x4 grid of 16x16x32 MFMAs. acc[tm][tn][reg] maps to
// C[wm*64+tm*16+quad*4+reg][wn*64+tn*16+(lane&15)]  (m89-verified C/D layout).
__device__ __forceinline__ void gemm128(const uint16_t* A, const uint16_t* B,
                                        uint16_t* As, uint16_t* Bs,
                                        f32x4 acc[4][4]) {
  const int lane = threadIdx.x & 63;
  const int wave = threadIdx.x >> 6;
  const int wm = wave >> 1, wn = wave & 1;
  const int quad = lane >> 4, rlo = lane & 15;

  const f32x4 zero = {0.f, 0.f, 0.f, 0.f};
#pragma unroll
  for (int tm = 0; tm < 4; ++tm)
#pragma unroll
    for (int tn = 0; tn < 4; ++tn) acc[tm][tn] = zero;

  for (int k0 = 0; k0 < DIM; k0 += BK) {
    stage_tile(A + k0, As, wave, lane);
    stage_tile(B + k0, Bs, wave, lane);
    __builtin_amdgcn_s_waitcnt(0x0F70);  // vmcnt(0) only
    __syncthreads();

    bf16x8 af[4], bf[4];
#pragma unroll
    for (int tm = 0; tm < 4; ++tm)
      af[tm] = *(const bf16x8*)&As[(wm * 64 + tm * 16 + rlo) * BK + quad * 8];
#pragma unroll
    for (int tn = 0; tn < 4; ++tn)
      bf[tn] = *(const bf16x8*)&Bs[(wn * 64 + tn * 16 + rlo) * BK + quad * 8];
#pragma unroll
    for (int tm = 0; tm < 4; ++tm)
#pragma unroll
      for (int tn = 0; tn < 4; ++tn)
        acc[tm][tn] = __builtin_amdgcn_mfma_f32_16x16x32_bf16(
            af[tm], bf[tn], acc[tm][tn], 0, 0, 0);
    __syncthreads();
  }
}

// ---------------- cast fp32 -> bf16 (vectorized x4) ----------------
__global__ void cast_kernel(const float* __restrict__ src,
                            uint16_t* __restrict__ dst, int n4) {
  int i = blockIdx.x * blockDim.x + threadIdx.x;
  if (i < n4) {
    float4 f = ((const float4*)src)[i];
    ushort4 o;
    o.x = f2bf(f.x); o.y = f2bf(f.y); o.z = f2bf(f.z); o.w = f2bf(f.w);
    ((ushort4*)dst)[i] = o;
  }
}

// ---------------- projections: QKV[w][p] = relu(xb[p] @ W[w]^T + b[w]) ------
__global__ __launch_bounds__(256) void proj_kernel(
    const uint16_t* __restrict__ xb, const uint16_t* __restrict__ Wb,
    const float* __restrict__ bq, const float* __restrict__ bk,
    const float* __restrict__ bv, uint16_t* __restrict__ QKV) {
  __shared__ __align__(16) uint16_t As[BM * BK];
  __shared__ __align__(16) uint16_t Bs[BN * BK];
  const int it = blockIdx.x, jt = blockIdx.y, z = blockIdx.z;
  const int w = z >> 1, p = z & 1;
  const uint16_t* A = xb + (size_t)p * (4 * S_LEN * DIM) + (size_t)it * BM * DIM;
  const uint16_t* B = Wb + (size_t)w * (DIM * DIM) + (size_t)jt * BN * DIM;
  const float* bias = (w == 0) ? bq : (w == 1) ? bk : bv;

  f32x4 acc[4][4];
  gemm128(A, B, As, Bs, acc);

  const int lane = threadIdx.x & 63, wave = threadIdx.x >> 6;
  const int wm = wave >> 1, wn = wave & 1, quad = lane >> 4, rlo = lane & 15;
  uint16_t* O = QKV + (size_t)(w * 2 + p) * (4 * S_LEN * DIM) +
                (size_t)it * BM * DIM;
#pragma unroll
  for (int tn = 0; tn < 4; ++tn) {
    int jc = jt * BN + wn * 64 + tn * 16 + rlo;
    float bj = bias[jc];
#pragma unroll
    for (int tm = 0; tm < 4; ++tm) {
#pragma unroll
      for (int r = 0; r < 4; ++r) {
        int i = wm * 64 + tm * 16 + quad * 4 + r;
        float v = acc[tm][tn][r] + bj;
        v = v > 0.f ? v : 0.f;
        O[(size_t)i * DIM + jc] = f2bf(v);
      }
    }
  }
}

// ------- s[which][b][i] += sum_j tanh(K[i,:].Q[j,:]) over this j-tile -------
__global__ __launch_bounds__(256) void tanhsum_kernel(
    const uint16_t* __restrict__ QKV, float* __restrict__ ssum) {
  __shared__ __align__(16) uint16_t As[BM * BK];
  __shared__ __align__(16) uint16_t Bs[BN * BK];
  const int it = blockIdx.x, jt = blockIdx.y, z = blockIdx.z;
  const int which = z >> 2, b = z & 3;
  const size_t T = (size_t)S_LEN * DIM;
  // s1: K from pair0 (which=0) dotted with Q from pair1, etc.
  const uint16_t* Kp = QKV + (size_t)((2 + which) * 4 + b) * T + (size_t)it * BM * DIM;
  const uint16_t* Qp = QKV + (size_t)(((which ^ 1)) * 4 + b) * T + (size_t)jt * BN * DIM;

  f32x4 acc[4][4];
  gemm128(Kp, Qp, As, Bs, acc);

  const int lane = threadIdx.x & 63, wave = threadIdx.x >> 6;
  const int wm = wave >> 1, quad = lane >> 4, rlo = lane & 15;
  float* srow = ssum + (size_t)(which * 4 + b) * S_LEN + it * BM;
#pragma unroll
  for (int tm = 0; tm < 4; ++tm) {
#pragma unroll
    for (int r = 0; r < 4; ++r) {
      float v = 0.f;
#pragma unroll
      for (int tn = 0; tn < 4; ++tn) v += tanh_fast(acc[tm][tn][r]);
      // reduce across the 16 column-lanes (bits 0..3 of lane)
      v += __shfl_xor(v, 8);
      v += __shfl_xor(v, 4);
      v += __shfl_xor(v, 2);
      v += __shfl_xor(v, 1);
      if (rlo == 0)
        atomicAdd(&srow[wm * 64 + tm * 16 + quad * 4 + r], v);
    }
  }
}

// ---------------- masked softmax over S, in place ----------------
__global__ __launch_bounds__(256) void softmax_kernel(
    float* __restrict__ ssum, const int* __restrict__ mask1,
    const int* __restrict__ mask2) {
  __shared__ float red[8];
  const int which = blockIdx.x >> 2, b = blockIdx.x & 3;
  const int* m = (which ? mask2 : mask1) + b * S_LEN;
  float* s = ssum + (size_t)(which * 4 + b) * S_LEN;
  const int tid = threadIdx.x;

  float lmax = -3.0e38f;
  for (int i = tid; i < S_LEN; i += 256)
    if (m[i] == 0) lmax = fmaxf(lmax, s[i]);
  for (int d = 32; d >= 1; d >>= 1) lmax = fmaxf(lmax, __shfl_xor(lmax, d));
  if ((tid & 63) == 0) red[tid >> 6] = lmax;
  __syncthreads();
  float gmax = fmaxf(fmaxf(red[0], red[1]), fmaxf(red[2], red[3]));

  float lsum = 0.f;
  for (int i = tid; i < S_LEN; i += 256) {
    float e = (m[i] == 0) ? __expf(s[i] - gmax) : 0.f;
    s[i] = e;
    lsum += e;
  }
  for (int d = 32; d >= 1; d >>= 1) lsum += __shfl_xor(lsum, d);
  if ((tid & 63) == 0) red[4 + (tid >> 6)] = lsum;
  __syncthreads();
  float inv = 1.0f / (red[4] + red[5] + red[6] + red[7]);
  for (int i = tid; i < S_LEN; i += 256) s[i] *= inv;
}

// -------- vec[which][b][d] = sum_s a[s]*V[s,d];  xmean accumulated too ------
__global__ __launch_bounds__(256) void vec_kernel(
    const float* __restrict__ a, const uint16_t* __restrict__ QKV,
    const float* __restrict__ x1, const float* __restrict__ x2,
    float* __restrict__ vec, float* __restrict__ xmean) {
  const int which = blockIdx.x >> 2, b = blockIdx.x & 3;
  const int chunk = blockIdx.y;
  const int d = threadIdx.x;
  const size_t T = (size_t)S_LEN * DIM;
  const uint16_t* V = QKV + (size_t)((4 + which) * 4 + b) * T;
  const float* x = (which ? x2 : x1) + (size_t)b * T;
  const float* aw = a + (size_t)(which * 4 + b) * S_LEN;

  float accv = 0.f, accx = 0.f;
  const int s0 = chunk * 256;
  for (int s = s0; s < s0 + 256; ++s) {
    accv += aw[s] * bf2f(V[(size_t)s * DIM + d]);
    accx += x[(size_t)s * DIM + d];
  }
  const int idx = (which * 4 + b) * DIM + d;
  atomicAdd(&vec[idx], accv);
  atomicAdd(&xmean[idx], accx * (1.0f / S_LEN));
}

// ---------------- layernorm(xmean + vec) ----------------
__global__ __launch_bounds__(256) void ln_kernel(
    const float* __restrict__ vec, const float* __restrict__ xmean,
    const float* __restrict__ gamma, const float* __restrict__ beta,
    float* __restrict__ out) {
  __shared__ float red[8];
  const int which = blockIdx.x >> 2, b = blockIdx.x & 3;
  const int d = threadIdx.x;
  const int idx = (which * 4 + b) * DIM + d;
  float y = xmean[idx] + vec[idx];

  float v = y;
  for (int m = 32; m >= 1; m >>= 1) v += __shfl_xor(v, m);
  if ((d & 63) == 0) red[d >> 6] = v;
  __syncthreads();
  float mu = (red[0] + red[1] + red[2] + red[3]) * (1.0f / DIM);
  __syncthreads();
  float c = y - mu;
  float v2 = c * c;
  for (int m = 32; m >= 1; m >>= 1) v2 += __shfl_xor(v2, m);
  if ((d & 63) == 0) red[4 + (d >> 6)] = v2;
  __syncthreads();
  float var = (red[4] + red[5] + red[6] + red[7]) * (1.0f / DIM);
  out[idx] = c * rsqrtf(var + 1e-5f) * gamma[d] + beta[d];
}

extern "C" void kernel_launch(void* const* d_in, const int* in_sizes, int n_in,
                              void* d_out, int out_size, void* d_ws,
                              size_t ws_size, hipStream_t stream) {
  (void)in_sizes; (void)n_in; (void)out_size; (void)ws_size;
  const float* x1 = (const float*)d_in[0];
  const float* x2 = (const float*)d_in[1];
  const int* mask1 = (const int*)d_in[2];
  const int* mask2 = (const int*)d_in[3];
  const float* Wq = (const float*)d_in[4];
  const float* bq = (const float*)d_in[5];
  const float* Wk = (const float*)d_in[6];
  const float* bk = (const float*)d_in[7];
  const float* Wv = (const float*)d_in[8];
  const float* bv = (const float*)d_in[9];
  const float* gamma = (const float*)d_in[10];
  const float* beta = (const float*)d_in[11];
  float* out = (float*)d_out;

  char* ws = (char*)d_ws;
  uint16_t* QKV = (uint16_t*)ws;                    // 50,331,648 B  [w][p][b][s][d]
  uint16_t* xb = (uint16_t*)(ws + 50331648);        // 16,777,216 B  [p][b][s][d]
  uint16_t* Wb = (uint16_t*)(ws + 67108864);        //    393,216 B  [w][d][e]
  float* ssum = (float*)(ws + 67502080);            //    131,072 B  [which][b][s]
  float* vec = (float*)(ws + 67633152);             //      8,192 B
  float* xmean = (float*)(ws + 67641344);           //      8,192 B

  (void)hipMemsetAsync(ws + 67502080, 0, 131072 + 8192 + 8192, stream);

  const int n4x = (4 * S_LEN * DIM) / 4;  // 1,048,576
  cast_kernel<<<dim3((n4x + 255) / 256), 256, 0, stream>>>(x1, xb, n4x);
  cast_kernel<<<dim3((n4x + 255) / 256), 256, 0, stream>>>(
      x2, xb + (size_t)4 * S_LEN * DIM, n4x);
  const int n4w = (DIM * DIM) / 4;  // 16,384
  cast_kernel<<<dim3((n4w + 255) / 256), 256, 0, stream>>>(Wq, Wb, n4w);
  cast_kernel<<<dim3((n4w + 255) / 256), 256, 0, stream>>>(Wk, Wb + DIM * DIM, n4w);
  cast_kernel<<<dim3((n4w + 255) / 256), 256, 0, stream>>>(Wv, Wb + 2 * DIM * DIM, n4w);

  proj_kernel<<<dim3(128, 2, 6), 256, 0, stream>>>(xb, Wb, bq, bk, bv, QKV);
  tanhsum_kernel<<<dim3(32, 32, 8), 256, 0, stream>>>(QKV, ssum);
  softmax_kernel<<<dim3(8), 256, 0, stream>>>(ssum, mask1, mask2);
  vec_kernel<<<dim3(8, 16), 256, 0, stream>>>(ssum, QKV, x1, x2, vec, xmean);
  ln_kernel<<<dim3(8), 256, 0, stream>>>(vec, xmean, gamma, beta, out);
}

// Round 2
// 230.670 us; speedup vs baseline: 1.2904x; 1.2904x over previous
//
#include <hip/hip_runtime.h>
#include <stdint.h>

#define S_LEN 4096
#define DIM 256
#define BM 128
#define BN 128
#define BK 32

// tanhsum v2 params
#define TS_WROWS 64   // i-rows per wave (in registers)
#define TS_IBLK 256   // i-rows per block (4 waves)
#define TS_JT 64      // j-rows per LDS tile
#define TS_JCH 4      // j-range splits (grid.y)
#define TS_JITERS (S_LEN / TS_JCH / TS_JT)  // 16

typedef short bf16x8 __attribute__((ext_vector_type(8)));
typedef float f32x4 __attribute__((ext_vector_type(4)));

typedef __attribute__((address_space(1))) void gv_t;
typedef __attribute__((address_space(3))) void lv_t;

__device__ __forceinline__ uint16_t f2bf(float f) {
  uint32_t u = __float_as_uint(f);
  return (uint16_t)((u + 0x7FFFu + ((u >> 16) & 1u)) >> 16);
}
__device__ __forceinline__ float bf2f(uint16_t h) {
  return __uint_as_float(((uint32_t)h) << 16);
}
// exact tanh for all x: t = e^{-2x}; tanh = 1 - 2t/(1+t).
// For saturated dots (t underflows) this is exactly 1.0f with zero error.
__device__ __forceinline__ float tanh_fast(float x) {
  float t = __builtin_amdgcn_exp2f(x * -2.885390082f);  // 2^(-2x*log2(e))
  return 1.0f - 2.0f * t * __builtin_amdgcn_rcpf(1.0f + t);
}

// ---- round-1 verified staging + 128x128 GEMM core (used by proj) ----
__device__ __forceinline__ void stage_tile(const uint16_t* gbase, uint16_t* lds,
                                           int wave, int lane) {
#pragma unroll
  for (int t = 0; t < 2; ++t) {
    int r = ((wave << 1) + t) * 16 + (lane >> 2);
    int c = (lane & 3) * 8;
    const uint16_t* g = gbase + r * DIM + c;
    uint16_t* l = lds + ((wave << 1) + t) * 512;  // wave-uniform LDS base
    __builtin_amdgcn_global_load_lds((gv_t*)g, (lv_t*)l, 16, 0, 0);
  }
}

__device__ __forceinline__ void gemm128(const uint16_t* A, const uint16_t* B,
                                        uint16_t* As, uint16_t* Bs,
                                        f32x4 acc[4][4]) {
  const int lane = threadIdx.x & 63;
  const int wave = threadIdx.x >> 6;
  const int wm = wave >> 1, wn = wave & 1;
  const int quad = lane >> 4, rlo = lane & 15;

  const f32x4 zero = {0.f, 0.f, 0.f, 0.f};
#pragma unroll
  for (int tm = 0; tm < 4; ++tm)
#pragma unroll
    for (int tn = 0; tn < 4; ++tn) acc[tm][tn] = zero;

  for (int k0 = 0; k0 < DIM; k0 += BK) {
    stage_tile(A + k0, As, wave, lane);
    stage_tile(B + k0, Bs, wave, lane);
    __builtin_amdgcn_s_waitcnt(0x0F70);  // vmcnt(0)
    __syncthreads();

    bf16x8 af[4], bf[4];
#pragma unroll
    for (int tm = 0; tm < 4; ++tm)
      af[tm] = *(const bf16x8*)&As[(wm * 64 + tm * 16 + rlo) * BK + quad * 8];
#pragma unroll
    for (int tn = 0; tn < 4; ++tn)
      bf[tn] = *(const bf16x8*)&Bs[(wn * 64 + tn * 16 + rlo) * BK + quad * 8];
#pragma unroll
    for (int tm = 0; tm < 4; ++tm)
#pragma unroll
      for (int tn = 0; tn < 4; ++tn)
        acc[tm][tn] = __builtin_amdgcn_mfma_f32_16x16x32_bf16(
            af[tm], bf[tn], acc[tm][tn], 0, 0, 0);
    __syncthreads();
  }
}

// ---------------- fused cast fp32 -> bf16 for all five inputs --------------
#define N4X 1048576  // (4*S_LEN*DIM)/4
#define N4W 16384    // (DIM*DIM)/4
__global__ __launch_bounds__(256) void cast_all_kernel(
    const float* __restrict__ x1, const float* __restrict__ x2,
    const float* __restrict__ Wq, const float* __restrict__ Wk,
    const float* __restrict__ Wv, uint16_t* __restrict__ dst) {
  int i = blockIdx.x * 256 + threadIdx.x;
  const int total = 2 * N4X + 3 * N4W;
  if (i >= total) return;
  const float* src;
  int j = i;
  if (j < N4X) {
    src = x1;
  } else if ((j -= N4X) < N4X) {
    src = x2;
  } else if ((j -= N4X) < N4W) {
    src = Wq;
  } else if ((j -= N4W) < N4W) {
    src = Wk;
  } else {
    j -= N4W;
    src = Wv;
  }
  float4 f = ((const float4*)src)[j];
  ushort4 o;
  o.x = f2bf(f.x); o.y = f2bf(f.y); o.z = f2bf(f.z); o.w = f2bf(f.w);
  ((ushort4*)dst)[i] = o;
}

// ---------------- projections: QKV[w][p] = relu(xb[p] @ W[w]^T + b[w]) ------
__global__ __launch_bounds__(256) void proj_kernel(
    const uint16_t* __restrict__ xb, const uint16_t* __restrict__ Wb,
    const float* __restrict__ bq, const float* __restrict__ bk,
    const float* __restrict__ bv, uint16_t* __restrict__ QKV) {
  __shared__ __align__(16) uint16_t As[BM * BK];
  __shared__ __align__(16) uint16_t Bs[BN * BK];
  const int it = blockIdx.x, jt = blockIdx.y, z = blockIdx.z;
  const int w = z >> 1, p = z & 1;
  const uint16_t* A = xb + (size_t)p * (4 * S_LEN * DIM) + (size_t)it * BM * DIM;
  const uint16_t* B = Wb + (size_t)w * (DIM * DIM) + (size_t)jt * BN * DIM;
  const float* bias = (w == 0) ? bq : (w == 1) ? bk : bv;

  f32x4 acc[4][4];
  gemm128(A, B, As, Bs, acc);

  const int lane = threadIdx.x & 63, wave = threadIdx.x >> 6;
  const int wm = wave >> 1, wn = wave & 1, quad = lane >> 4, rlo = lane & 15;
  uint16_t* O = QKV + (size_t)(w * 2 + p) * (4 * S_LEN * DIM) +
                (size_t)it * BM * DIM;
#pragma unroll
  for (int tn = 0; tn < 4; ++tn) {
    int jc = jt * BN + wn * 64 + tn * 16 + rlo;
    float bj = bias[jc];
#pragma unroll
    for (int tm = 0; tm < 4; ++tm) {
#pragma unroll
      for (int r = 0; r < 4; ++r) {
        int i = wm * 64 + tm * 16 + quad * 4 + r;
        float v = acc[tm][tn][r] + bj;
        v = v > 0.f ? v : 0.f;
        O[(size_t)i * DIM + jc] = f2bf(v);
      }
    }
  }
}

// ---- tanhsum v2: per-block 256 i-rows (K-frags in regs), j-tiles streamed
// ---- through double-buffered LDS; tanh folded into per-lane running sums.
__global__ __launch_bounds__(256, 2) void tanhsum_kernel(
    const uint16_t* __restrict__ QKV, float* __restrict__ ssum) {
  __shared__ __align__(16) uint16_t Bsh[2][TS_JT * DIM];  // 2 x 32KB
  const int tid = threadIdx.x;
  const int lane = tid & 63, wave = tid >> 6;
  const int quad = lane >> 4, rlo = lane & 15;
  const int it = blockIdx.x, jcch = blockIdx.y, z = blockIdx.z;
  const int which = z >> 2, b = z & 3;
  const size_t T = (size_t)S_LEN * DIM;
  const uint16_t* Kp = QKV + (size_t)((2 + which) * 4 + b) * T;
  const uint16_t* Qp = QKV + (size_t)((which ^ 1) * 4 + b) * T;

  // A fragments: this wave's 64 K-rows x full K=256, persistent in VGPRs.
  bf16x8 aA[4][8];
  {
    const uint16_t* Ab =
        Kp + (size_t)(it * TS_IBLK + wave * TS_WROWS + rlo) * DIM + quad * 8;
#pragma unroll
    for (int tm = 0; tm < 4; ++tm)
#pragma unroll
      for (int kc = 0; kc < 8; ++kc)
        aA[tm][kc] = *(const bf16x8*)(Ab + (size_t)tm * 16 * DIM + kc * 32);
  }

  float srun[4][4];
#pragma unroll
  for (int tm = 0; tm < 4; ++tm)
#pragma unroll
    for (int r = 0; r < 4; ++r) srun[tm][r] = 0.f;

  const int jbase0 = jcch * (S_LEN / TS_JCH);

  // Stage j-tile jj into buffer buf. 64 rows x 256 cols bf16 = 2048 x 16B
  // chunks; chunk placement XOR-swizzled by row so stride-512B B-frag reads
  // hit distinct banks. LDS side stays lane-contiguous (global_load_lds req).
  auto stage = [&](int jj, int buf) {
    const uint16_t* Qt = Qp + (size_t)(jbase0 + jj * TS_JT) * DIM;
    uint16_t* L = &Bsh[buf][0];
#pragma unroll
    for (int rho = 0; rho < 8; ++rho) {
      int s = rho * 256 + tid;
      int r = s >> 5, cs = s & 31;
      int cg = cs ^ (r & 15);
      const uint16_t* g = Qt + r * DIM + cg * 8;
      uint16_t* l = L + (rho * 256 + wave * 64) * 8;  // wave-uniform base
      __builtin_amdgcn_global_load_lds((gv_t*)g, (lv_t*)l, 16, 0, 0);
    }
  };

  stage(0, 0);
  __builtin_amdgcn_s_waitcnt(0x0F70);  // vmcnt(0)
  __syncthreads();

  for (int jj = 0; jj < TS_JITERS; ++jj) {
    const int buf = jj & 1;
    if (jj + 1 < TS_JITERS) stage(jj + 1, buf ^ 1);  // overlaps compute below
    const uint16_t* L = &Bsh[buf][0];
#pragma unroll
    for (int tn = 0; tn < 4; ++tn) {
      bf16x8 bfr[8];
      const int rowl = tn * 16 + rlo;
#pragma unroll
      for (int kc = 0; kc < 8; ++kc) {
        int slot = (kc * 4 + quad) ^ rlo;  // undo staging swizzle
        bfr[kc] = *(const bf16x8*)&L[rowl * DIM + slot * 8];
      }
      f32x4 acc[4];
      const f32x4 zero = {0.f, 0.f, 0.f, 0.f};
#pragma unroll
      for (int tm = 0; tm < 4; ++tm) acc[tm] = zero;
#pragma unroll
      for (int kc = 0; kc < 8; ++kc)
#pragma unroll
        for (int tm = 0; tm < 4; ++tm)
          acc[tm] = __builtin_amdgcn_mfma_f32_16x16x32_bf16(
              aA[tm][kc], bfr[kc], acc[tm], 0, 0, 0);
#pragma unroll
      for (int tm = 0; tm < 4; ++tm)
#pragma unroll
        for (int r = 0; r < 4; ++r) srun[tm][r] += tanh_fast(acc[tm][r]);
    }
    __builtin_amdgcn_s_waitcnt(0x0F70);  // vmcnt(0): staging landed
    __syncthreads();
  }

  // Reduce partial row-sums over the 16 column-lanes; one atomic per row.
  float* srow = ssum + (size_t)z * S_LEN + it * TS_IBLK + wave * TS_WROWS;
#pragma unroll
  for (int tm = 0; tm < 4; ++tm)
#pragma unroll
    for (int r = 0; r < 4; ++r) {
      float v = srun[tm][r];
      v += __shfl_xor(v, 1);
      v += __shfl_xor(v, 2);
      v += __shfl_xor(v, 4);
      v += __shfl_xor(v, 8);
      if (rlo == 0) atomicAdd(&srow[tm * 16 + quad * 4 + r], v);
    }
}

// ---------------- masked softmax over S, in place ----------------
__global__ __launch_bounds__(256) void softmax_kernel(
    float* __restrict__ ssum, const int* __restrict__ mask1,
    const int* __restrict__ mask2) {
  __shared__ float red[8];
  const int which = blockIdx.x >> 2, b = blockIdx.x & 3;
  const int* m = (which ? mask2 : mask1) + b * S_LEN;
  float* s = ssum + (size_t)(which * 4 + b) * S_LEN;
  const int tid = threadIdx.x;

  float lmax = -3.0e38f;
  for (int i = tid; i < S_LEN; i += 256)
    if (m[i] == 0) lmax = fmaxf(lmax, s[i]);
  for (int d = 32; d >= 1; d >>= 1) lmax = fmaxf(lmax, __shfl_xor(lmax, d));
  if ((tid & 63) == 0) red[tid >> 6] = lmax;
  __syncthreads();
  float gmax = fmaxf(fmaxf(red[0], red[1]), fmaxf(red[2], red[3]));

  float lsum = 0.f;
  for (int i = tid; i < S_LEN; i += 256) {
    float e = (m[i] == 0) ? __expf(s[i] - gmax) : 0.f;
    s[i] = e;
    lsum += e;
  }
  for (int d = 32; d >= 1; d >>= 1) lsum += __shfl_xor(lsum, d);
  if ((tid & 63) == 0) red[4 + (tid >> 6)] = lsum;
  __syncthreads();
  float inv = 1.0f / (red[4] + red[5] + red[6] + red[7]);
  for (int i = tid; i < S_LEN; i += 256) s[i] *= inv;
}

// -------- vec[which][b][d] = sum_s a[s]*V[s,d];  xmean accumulated too ------
__global__ __launch_bounds__(256) void vec_kernel(
    const float* __restrict__ a, const uint16_t* __restrict__ QKV,
    const uint16_t* __restrict__ xb, float* __restrict__ vec,
    float* __restrict__ xmean) {
  const int which = blockIdx.x >> 2, b = blockIdx.x & 3;
  const int chunk = blockIdx.y;  // 0..31 -> 128 rows each
  const int d = threadIdx.x;
  const size_t T = (size_t)S_LEN * DIM;
  const uint16_t* V = QKV + (size_t)((4 + which) * 4 + b) * T;
  const uint16_t* x = xb + (size_t)(which * 4 + b) * T;
  const float* aw = a + (size_t)(which * 4 + b) * S_LEN;

  float accv = 0.f, accx = 0.f;
  const int s0 = chunk * 128;
  for (int s = s0; s < s0 + 128; ++s) {
    accv += aw[s] * bf2f(V[(size_t)s * DIM + d]);
    accx += bf2f(x[(size_t)s * DIM + d]);
  }
  const int idx = (which * 4 + b) * DIM + d;
  atomicAdd(&vec[idx], accv);
  atomicAdd(&xmean[idx], accx * (1.0f / S_LEN));
}

// ---------------- layernorm(xmean + vec) ----------------
__global__ __launch_bounds__(256) void ln_kernel(
    const float* __restrict__ vec, const float* __restrict__ xmean,
    const float* __restrict__ gamma, const float* __restrict__ beta,
    float* __restrict__ out) {
  __shared__ float red[8];
  const int which = blockIdx.x >> 2, b = blockIdx.x & 3;
  const int d = threadIdx.x;
  const int idx = (which * 4 + b) * DIM + d;
  float y = xmean[idx] + vec[idx];

  float v = y;
  for (int m = 32; m >= 1; m >>= 1) v += __shfl_xor(v, m);
  if ((d & 63) == 0) red[d >> 6] = v;
  __syncthreads();
  float mu = (red[0] + red[1] + red[2] + red[3]) * (1.0f / DIM);
  __syncthreads();
  float c = y - mu;
  float v2 = c * c;
  for (int m = 32; m >= 1; m >>= 1) v2 += __shfl_xor(v2, m);
  if ((d & 63) == 0) red[4 + (d >> 6)] = v2;
  __syncthreads();
  float var = (red[4] + red[5] + red[6] + red[7]) * (1.0f / DIM);
  out[idx] = c * rsqrtf(var + 1e-5f) * gamma[d] + beta[d];
}

extern "C" void kernel_launch(void* const* d_in, const int* in_sizes, int n_in,
                              void* d_out, int out_size, void* d_ws,
                              size_t ws_size, hipStream_t stream) {
  (void)in_sizes; (void)n_in; (void)out_size; (void)ws_size;
  const float* x1 = (const float*)d_in[0];
  const float* x2 = (const float*)d_in[1];
  const int* mask1 = (const int*)d_in[2];
  const int* mask2 = (const int*)d_in[3];
  const float* Wq = (const float*)d_in[4];
  const float* bq = (const float*)d_in[5];
  const float* Wk = (const float*)d_in[6];
  const float* bk = (const float*)d_in[7];
  const float* Wv = (const float*)d_in[8];
  const float* bv = (const float*)d_in[9];
  const float* gamma = (const float*)d_in[10];
  const float* beta = (const float*)d_in[11];
  float* out = (float*)d_out;

  char* ws = (char*)d_ws;
  uint16_t* QKV = (uint16_t*)ws;              // 50,331,648 B  [w][p][b][s][d]
  uint16_t* xb = (uint16_t*)(ws + 50331648);  // 16,777,216 B  [p][b][s][d]
  uint16_t* Wb = (uint16_t*)(ws + 67108864);  //    393,216 B  [w][d][e]
  float* ssum = (float*)(ws + 67502080);      //    131,072 B  [which][b][s]
  float* vec = (float*)(ws + 67633152);       //      8,192 B
  float* xmean = (float*)(ws + 67641344);     //      8,192 B

  (void)hipMemsetAsync(ws + 67502080, 0, 131072 + 8192 + 8192, stream);

  const int total4 = 2 * N4X + 3 * N4W;  // 2,146,304 float4 groups
  cast_all_kernel<<<dim3((total4 + 255) / 256), 256, 0, stream>>>(
      x1, x2, Wq, Wk, Wv, xb);  // xb and Wb are contiguous in ws

  proj_kernel<<<dim3(128, 2, 6), 256, 0, stream>>>(xb, Wb, bq, bk, bv, QKV);
  tanhsum_kernel<<<dim3(16, TS_JCH, 8), 256, 0, stream>>>(QKV, ssum);
  softmax_kernel<<<dim3(8), 256, 0, stream>>>(ssum, mask1, mask2);
  vec_kernel<<<dim3(8, 32), 256, 0, stream>>>(ssum, QKV, xb, vec, xmean);
  ln_kernel<<<dim3(8), 256, 0, stream>>>(vec, xmean, gamma, beta, out);
}

// Round 3
// 217.338 us; speedup vs baseline: 1.3695x; 1.0613x over previous
//
#include <hip/hip_runtime.h>
#include <stdint.h>

#define S_LEN 4096
#define DIM 256

// tanhsum params
#define TS_WROWS 64   // i-rows per wave (in registers)
#define TS_IBLK 256   // i-rows per block (4 waves)
#define TS_JT 64      // j-rows per LDS tile
#define TS_JCH 4      // j-range splits (grid.y)
#define TS_JITERS (S_LEN / TS_JCH / TS_JT)  // 16

typedef short bf16x8 __attribute__((ext_vector_type(8)));
typedef float f32x4 __attribute__((ext_vector_type(4)));

typedef __attribute__((address_space(1))) void gv_t;
typedef __attribute__((address_space(3))) void lv_t;

__device__ __forceinline__ uint16_t f2bf(float f) {
  uint32_t u = __float_as_uint(f);
  return (uint16_t)((u + 0x7FFFu + ((u >> 16) & 1u)) >> 16);
}
__device__ __forceinline__ float bf2f(uint16_t h) {
  return __uint_as_float(((uint32_t)h) << 16);
}
// exact tanh for all x: t = e^{-2x}; tanh = 1 - 2t/(1+t).
// For saturated dots (t underflows) this is exactly 1.0f.
__device__ __forceinline__ float tanh_fast(float x) {
  float t = __builtin_amdgcn_exp2f(x * -2.885390082f);  // 2^(-2x*log2(e))
  return 1.0f - 2.0f * t * __builtin_amdgcn_rcpf(1.0f + t);
}
__device__ __forceinline__ f32x4 fmin4(f32x4 a, f32x4 b) {
  f32x4 r;
  r[0] = fminf(a[0], b[0]); r[1] = fminf(a[1], b[1]);
  r[2] = fminf(a[2], b[2]); r[3] = fminf(a[3], b[3]);
  return r;
}

// Stage a 64x256 bf16 tile (row stride DIM) into LDS, 16B/lane async DMA.
// Chunk placement XOR-swizzled by row so stride-512B fragment reads are
// bank-conflict-free (verified: 8.4M conflicts -> 0 in round 2).
__device__ __forceinline__ void stage64(const uint16_t* __restrict__ src,
                                        uint16_t* lds, int tid, int wave) {
#pragma unroll
  for (int rho = 0; rho < 8; ++rho) {
    int s = rho * 256 + tid;
    int r = s >> 5, cs = s & 31;
    int cg = cs ^ (r & 15);
    const uint16_t* g = src + r * DIM + cg * 8;
    uint16_t* l = lds + (rho * 256 + wave * 64) * 8;  // wave-uniform base
    __builtin_amdgcn_global_load_lds((gv_t*)g, (lv_t*)l, 16, 0, 0);
  }
}

// Read the 8 K-chunks of B-fragment row `rowl`, undoing the staging swizzle.
__device__ __forceinline__ void read_bfr(const uint16_t* L, int rowl, int quad,
                                         int rlo, bf16x8* bfr) {
#pragma unroll
  for (int kc = 0; kc < 8; ++kc) {
    int slot = (kc * 4 + quad) ^ rlo;
    bfr[kc] = *(const bf16x8*)&L[rowl * DIM + slot * 8];
  }
}

// ---------------- fused cast fp32 -> bf16 for all five inputs --------------
#define N4X 1048576  // (4*S_LEN*DIM)/4
#define N4W 16384    // (DIM*DIM)/4
__global__ __launch_bounds__(256) void cast_all_kernel(
    const float* __restrict__ x1, const float* __restrict__ x2,
    const float* __restrict__ Wq, const float* __restrict__ Wk,
    const float* __restrict__ Wv, uint16_t* __restrict__ dst) {
  int i = blockIdx.x * 256 + threadIdx.x;
  const int total = 2 * N4X + 3 * N4W;
  if (i >= total) return;
  const float* src;
  int j = i;
  if (j < N4X) {
    src = x1;
  } else if ((j -= N4X) < N4X) {
    src = x2;
  } else if ((j -= N4X) < N4W) {
    src = Wq;
  } else if ((j -= N4W) < N4W) {
    src = Wk;
  } else {
    j -= N4W;
    src = Wv;
  }
  float4 f = ((const float4*)src)[j];
  ushort4 o;
  o.x = f2bf(f.x); o.y = f2bf(f.y); o.z = f2bf(f.z); o.w = f2bf(f.w);
  ((ushort4*)dst)[i] = o;
}

// ---- proj v3: QKV[w][p] = relu(xb[p] @ W[w]^T + b[w]).
// x-rows resident in registers (64/wave, loaded once); W (128KB, L2-hot)
// streamed through double-buffered LDS j-tiles. One barrier pair per 64 cols.
__global__ __launch_bounds__(256) void proj_kernel(
    const uint16_t* __restrict__ xb, const uint16_t* __restrict__ Wb,
    const float* __restrict__ bq, const float* __restrict__ bk,
    const float* __restrict__ bv, uint16_t* __restrict__ QKV) {
  __shared__ __align__(16) uint16_t Bsh[2][TS_JT * DIM];  // 2 x 32KB
  const int tid = threadIdx.x, lane = tid & 63, wave = tid >> 6;
  const int quad = lane >> 4, rlo = lane & 15;
  const int it = blockIdx.x, z = blockIdx.y;
  const int w = z >> 1, p = z & 1;
  const float* bias = (w == 0) ? bq : (w == 1) ? bk : bv;
  const size_t T4 = (size_t)4 * S_LEN * DIM;

  // A fragments: this wave's 64 x-rows, full K=256, persistent in regs.
  bf16x8 aA[4][8];
  {
    const uint16_t* Ab =
        xb + p * T4 + (size_t)(it * 256 + wave * 64 + rlo) * DIM + quad * 8;
#pragma unroll
    for (int tm = 0; tm < 4; ++tm)
#pragma unroll
      for (int kc = 0; kc < 8; ++kc)
        aA[tm][kc] = *(const bf16x8*)(Ab + (size_t)tm * 16 * DIM + kc * 32);
  }

  const uint16_t* Wt = Wb + w * (DIM * DIM);
  stage64(Wt, &Bsh[0][0], tid, wave);
  __builtin_amdgcn_s_waitcnt(0x0F70);  // vmcnt(0)
  __syncthreads();

  uint16_t* O =
      QKV + (size_t)(w * 2 + p) * T4 + (size_t)(it * 256 + wave * 64) * DIM;

  for (int jj = 0; jj < 4; ++jj) {
    const int buf = jj & 1;
    if (jj < 3) stage64(Wt + (jj + 1) * TS_JT * DIM, &Bsh[buf ^ 1][0], tid, wave);
    const uint16_t* L = &Bsh[buf][0];
#pragma unroll
    for (int tn = 0; tn < 4; ++tn) {
      bf16x8 bfr[8];
      read_bfr(L, tn * 16 + rlo, quad, rlo, bfr);
      f32x4 acc[4];
      const f32x4 zero = {0.f, 0.f, 0.f, 0.f};
#pragma unroll
      for (int tm = 0; tm < 4; ++tm) acc[tm] = zero;
#pragma unroll
      for (int kc = 0; kc < 8; ++kc)
#pragma unroll
        for (int tm = 0; tm < 4; ++tm)
          acc[tm] = __builtin_amdgcn_mfma_f32_16x16x32_bf16(
              aA[tm][kc], bfr[kc], acc[tm], 0, 0, 0);
      const int jc = jj * TS_JT + tn * 16 + rlo;
      const float bj = bias[jc];
#pragma unroll
      for (int tm = 0; tm < 4; ++tm)
#pragma unroll
        for (int r = 0; r < 4; ++r) {
          float v = acc[tm][r] + bj;
          v = v > 0.f ? v : 0.f;
          O[(size_t)(tm * 16 + quad * 4 + r) * DIM + jc] = f2bf(v);
        }
    }
    __builtin_amdgcn_s_waitcnt(0x0F70);  // staging (+stores) drained
    __syncthreads();
  }
}

// ---- tanhsum: K-frags in regs, Q j-tiles through double-buffered LDS;
// ---- saturated tanh (dot>10 -> exactly 1.0f) skipped via wave-coherent test.
__global__ __launch_bounds__(256, 2) void tanhsum_kernel(
    const uint16_t* __restrict__ QKV, float* __restrict__ ssum) {
  __shared__ __align__(16) uint16_t Bsh[2][TS_JT * DIM];  // 2 x 32KB
  const int tid = threadIdx.x;
  const int lane = tid & 63, wave = tid >> 6;
  const int quad = lane >> 4, rlo = lane & 15;
  const int it = blockIdx.x, jcch = blockIdx.y, z = blockIdx.z;
  const int which = z >> 2, b = z & 3;
  const size_t T = (size_t)S_LEN * DIM;
  const uint16_t* Kp = QKV + (size_t)((2 + which) * 4 + b) * T;
  const uint16_t* Qp = QKV + (size_t)((which ^ 1) * 4 + b) * T;

  bf16x8 aA[4][8];
  {
    const uint16_t* Ab =
        Kp + (size_t)(it * TS_IBLK + wave * TS_WROWS + rlo) * DIM + quad * 8;
#pragma unroll
    for (int tm = 0; tm < 4; ++tm)
#pragma unroll
      for (int kc = 0; kc < 8; ++kc)
        aA[tm][kc] = *(const bf16x8*)(Ab + (size_t)tm * 16 * DIM + kc * 32);
  }

  float srun[4][4];
#pragma unroll
  for (int tm = 0; tm < 4; ++tm)
#pragma unroll
    for (int r = 0; r < 4; ++r) srun[tm][r] = 0.f;

  const uint16_t* Qbase = Qp + (size_t)(jcch * (S_LEN / TS_JCH)) * DIM;

  stage64(Qbase, &Bsh[0][0], tid, wave);
  __builtin_amdgcn_s_waitcnt(0x0F70);  // vmcnt(0)
  __syncthreads();

  for (int jj = 0; jj < TS_JITERS; ++jj) {
    const int buf = jj & 1;
    if (jj + 1 < TS_JITERS)
      stage64(Qbase + (size_t)(jj + 1) * TS_JT * DIM, &Bsh[buf ^ 1][0], tid, wave);
    const uint16_t* L = &Bsh[buf][0];
#pragma unroll
    for (int tn = 0; tn < 4; ++tn) {
      bf16x8 bfr[8];
      read_bfr(L, tn * 16 + rlo, quad, rlo, bfr);
      f32x4 acc[4];
      const f32x4 zero = {0.f, 0.f, 0.f, 0.f};
#pragma unroll
      for (int tm = 0; tm < 4; ++tm) acc[tm] = zero;
#pragma unroll
      for (int kc = 0; kc < 8; ++kc)
#pragma unroll
        for (int tm = 0; tm < 4; ++tm)
          acc[tm] = __builtin_amdgcn_mfma_f32_16x16x32_bf16(
              aA[tm][kc], bfr[kc], acc[tm], 0, 0, 0);
      // Saturation skip: tanh(x) == 1.0f exactly (fp32) for x > 10, and
      // tanh_fast returns exactly 1.0f there too -- bit-identical fast path.
      f32x4 m4 = fmin4(fmin4(acc[0], acc[1]), fmin4(acc[2], acc[3]));
      float mn = fminf(fminf(m4[0], m4[1]), fminf(m4[2], m4[3]));
      if (__all(mn > 10.0f)) {
#pragma unroll
        for (int tm = 0; tm < 4; ++tm)
#pragma unroll
          for (int r = 0; r < 4; ++r) srun[tm][r] += 1.0f;
      } else {
#pragma unroll
        for (int tm = 0; tm < 4; ++tm)
#pragma unroll
          for (int r = 0; r < 4; ++r) srun[tm][r] += tanh_fast(acc[tm][r]);
      }
    }
    __builtin_amdgcn_s_waitcnt(0x0F70);  // staging landed
    __syncthreads();
  }

  float* srow = ssum + (size_t)z * S_LEN + it * TS_IBLK + wave * TS_WROWS;
#pragma unroll
  for (int tm = 0; tm < 4; ++tm)
#pragma unroll
    for (int r = 0; r < 4; ++r) {
      float v = srun[tm][r];
      v += __shfl_xor(v, 1);
      v += __shfl_xor(v, 2);
      v += __shfl_xor(v, 4);
      v += __shfl_xor(v, 8);
      if (rlo == 0) atomicAdd(&srow[tm * 16 + quad * 4 + r], v);
    }
}

// ---------------- masked softmax over S, in place ----------------
__global__ __launch_bounds__(256) void softmax_kernel(
    float* __restrict__ ssum, const int* __restrict__ mask1,
    const int* __restrict__ mask2) {
  __shared__ float red[8];
  const int which = blockIdx.x >> 2, b = blockIdx.x & 3;
  const int* m = (which ? mask2 : mask1) + b * S_LEN;
  float* s = ssum + (size_t)(which * 4 + b) * S_LEN;
  const int tid = threadIdx.x;

  float lmax = -3.0e38f;
  for (int i = tid; i < S_LEN; i += 256)
    if (m[i] == 0) lmax = fmaxf(lmax, s[i]);
  for (int d = 32; d >= 1; d >>= 1) lmax = fmaxf(lmax, __shfl_xor(lmax, d));
  if ((tid & 63) == 0) red[tid >> 6] = lmax;
  __syncthreads();
  float gmax = fmaxf(fmaxf(red[0], red[1]), fmaxf(red[2], red[3]));

  float lsum = 0.f;
  for (int i = tid; i < S_LEN; i += 256) {
    float e = (m[i] == 0) ? __expf(s[i] - gmax) : 0.f;
    s[i] = e;
    lsum += e;
  }
  for (int d = 32; d >= 1; d >>= 1) lsum += __shfl_xor(lsum, d);
  if ((tid & 63) == 0) red[4 + (tid >> 6)] = lsum;
  __syncthreads();
  float inv = 1.0f / (red[4] + red[5] + red[6] + red[7]);
  for (int i = tid; i < S_LEN; i += 256) s[i] *= inv;
}

// -------- vec[which][b][d] = sum_s a[s]*V[s,d];  xmean accumulated too ------
__global__ __launch_bounds__(256) void vec_kernel(
    const float* __restrict__ a, const uint16_t* __restrict__ QKV,
    const uint16_t* __restrict__ xb, float* __restrict__ vec,
    float* __restrict__ xmean) {
  const int which = blockIdx.x >> 2, b = blockIdx.x & 3;
  const int chunk = blockIdx.y;  // 0..31 -> 128 rows each
  const int d = threadIdx.x;
  const size_t T = (size_t)S_LEN * DIM;
  const uint16_t* V = QKV + (size_t)((4 + which) * 4 + b) * T;
  const uint16_t* x = xb + (size_t)(which * 4 + b) * T;
  const float* aw = a + (size_t)(which * 4 + b) * S_LEN;

  float accv = 0.f, accx = 0.f;
  const int s0 = chunk * 128;
  for (int s = s0; s < s0 + 128; ++s) {
    accv += aw[s] * bf2f(V[(size_t)s * DIM + d]);
    accx += bf2f(x[(size_t)s * DIM + d]);
  }
  const int idx = (which * 4 + b) * DIM + d;
  atomicAdd(&vec[idx], accv);
  atomicAdd(&xmean[idx], accx * (1.0f / S_LEN));
}

// ---------------- layernorm(xmean + vec) ----------------
__global__ __launch_bounds__(256) void ln_kernel(
    const float* __restrict__ vec, const float* __restrict__ xmean,
    const float* __restrict__ gamma, const float* __restrict__ beta,
    float* __restrict__ out) {
  __shared__ float red[8];
  const int which = blockIdx.x >> 2, b = blockIdx.x & 3;
  const int d = threadIdx.x;
  const int idx = (which * 4 + b) * DIM + d;
  float y = xmean[idx] + vec[idx];

  float v = y;
  for (int m = 32; m >= 1; m >>= 1) v += __shfl_xor(v, m);
  if ((d & 63) == 0) red[d >> 6] = v;
  __syncthreads();
  float mu = (red[0] + red[1] + red[2] + red[3]) * (1.0f / DIM);
  __syncthreads();
  float c = y - mu;
  float v2 = c * c;
  for (int m = 32; m >= 1; m >>= 1) v2 += __shfl_xor(v2, m);
  if ((d & 63) == 0) red[4 + (d >> 6)] = v2;
  __syncthreads();
  float var = (red[4] + red[5] + red[6] + red[7]) * (1.0f / DIM);
  out[idx] = c * rsqrtf(var + 1e-5f) * gamma[d] + beta[d];
}

extern "C" void kernel_launch(void* const* d_in, const int* in_sizes, int n_in,
                              void* d_out, int out_size, void* d_ws,
                              size_t ws_size, hipStream_t stream) {
  (void)in_sizes; (void)n_in; (void)out_size; (void)ws_size;
  const float* x1 = (const float*)d_in[0];
  const float* x2 = (const float*)d_in[1];
  const int* mask1 = (const int*)d_in[2];
  const int* mask2 = (const int*)d_in[3];
  const float* Wq = (const float*)d_in[4];
  const float* bq = (const float*)d_in[5];
  const float* Wk = (const float*)d_in[6];
  const float* bk = (const float*)d_in[7];
  const float* Wv = (const float*)d_in[8];
  const float* bv = (const float*)d_in[9];
  const float* gamma = (const float*)d_in[10];
  const float* beta = (const float*)d_in[11];
  float* out = (float*)d_out;

  char* ws = (char*)d_ws;
  uint16_t* QKV = (uint16_t*)ws;              // 50,331,648 B  [w][p][b][s][d]
  uint16_t* xb = (uint16_t*)(ws + 50331648);  // 16,777,216 B  [p][b][s][d]
  uint16_t* Wb = (uint16_t*)(ws + 67108864);  //    393,216 B  [w][d][e]
  float* ssum = (float*)(ws + 67502080);      //    131,072 B  [which][b][s]
  float* vec = (float*)(ws + 67633152);       //      8,192 B
  float* xmean = (float*)(ws + 67641344);     //      8,192 B

  (void)hipMemsetAsync(ws + 67502080, 0, 131072 + 8192 + 8192, stream);

  const int total4 = 2 * N4X + 3 * N4W;
  cast_all_kernel<<<dim3((total4 + 255) / 256), 256, 0, stream>>>(
      x1, x2, Wq, Wk, Wv, xb);  // xb and Wb are contiguous in ws

  proj_kernel<<<dim3(64, 6), 256, 0, stream>>>(xb, Wb, bq, bk, bv, QKV);
  tanhsum_kernel<<<dim3(16, TS_JCH, 8), 256, 0, stream>>>(QKV, ssum);
  softmax_kernel<<<dim3(8), 256, 0, stream>>>(ssum, mask1, mask2);
  vec_kernel<<<dim3(8, 32), 256, 0, stream>>>(ssum, QKV, xb, vec, xmean);
  ln_kernel<<<dim3(8), 256, 0, stream>>>(vec, xmean, gamma, beta, out);
}

// Round 4
// 206.430 us; speedup vs baseline: 1.4419x; 1.0528x over previous
//
#include <hip/hip_runtime.h>
#include <stdint.h>

#define S_LEN 4096
#define DIM 256

// tanhsum params
#define TS_WROWS 64   // i-rows per wave (in registers)
#define TS_IBLK 256   // i-rows per block (4 waves)
#define TS_JT 64      // j-rows per LDS tile
#define TS_JCH 4      // j-range splits (grid.y)
#define TS_JITERS (S_LEN / TS_JCH / TS_JT)  // 16

typedef short bf16x8 __attribute__((ext_vector_type(8)));
typedef float f32x4 __attribute__((ext_vector_type(4)));

typedef __attribute__((address_space(1))) void gv_t;
typedef __attribute__((address_space(3))) void lv_t;

__device__ __forceinline__ uint16_t f2bf(float f) {
  uint32_t u = __float_as_uint(f);
  return (uint16_t)((u + 0x7FFFu + ((u >> 16) & 1u)) >> 16);
}
__device__ __forceinline__ float bf2f(uint16_t h) {
  return __uint_as_float(((uint32_t)h) << 16);
}
// exact tanh for all x: t = e^{-2x}; tanh = 1 - 2t/(1+t).
// For saturated dots (t underflows) this is exactly 1.0f.
__device__ __forceinline__ float tanh_fast(float x) {
  float t = __builtin_amdgcn_exp2f(x * -2.885390082f);  // 2^(-2x*log2(e))
  return 1.0f - 2.0f * t * __builtin_amdgcn_rcpf(1.0f + t);
}
__device__ __forceinline__ f32x4 fmin4(f32x4 a, f32x4 b) {
  f32x4 r;
  r[0] = fminf(a[0], b[0]); r[1] = fminf(a[1], b[1]);
  r[2] = fminf(a[2], b[2]); r[3] = fminf(a[3], b[3]);
  return r;
}

// Stage a 64x256 bf16 tile (row stride DIM) into LDS, 16B/lane async DMA.
// Chunk placement XOR-swizzled by row so stride-512B fragment reads are
// bank-conflict-free (verified: 8.4M conflicts -> 0 in round 2).
__device__ __forceinline__ void stage64(const uint16_t* __restrict__ src,
                                        uint16_t* lds, int tid, int wave) {
#pragma unroll
  for (int rho = 0; rho < 8; ++rho) {
    int s = rho * 256 + tid;
    int r = s >> 5, cs = s & 31;
    int cg = cs ^ (r & 15);
    const uint16_t* g = src + r * DIM + cg * 8;
    uint16_t* l = lds + (rho * 256 + wave * 64) * 8;  // wave-uniform base
    __builtin_amdgcn_global_load_lds((gv_t*)g, (lv_t*)l, 16, 0, 0);
  }
}

// Read the 8 K-chunks of B-fragment row `rowl`, undoing the staging swizzle.
__device__ __forceinline__ void read_bfr(const uint16_t* L, int rowl, int quad,
                                         int rlo, bf16x8* bfr) {
#pragma unroll
  for (int kc = 0; kc < 8; ++kc) {
    int slot = (kc * 4 + quad) ^ rlo;
    bfr[kc] = *(const bf16x8*)&L[rowl * DIM + slot * 8];
  }
}

// ---------------- fused cast fp32 -> bf16 for all five inputs --------------
#define N4X 1048576  // (4*S_LEN*DIM)/4
#define N4W 16384    // (DIM*DIM)/4
__global__ __launch_bounds__(256) void cast_all_kernel(
    const float* __restrict__ x1, const float* __restrict__ x2,
    const float* __restrict__ Wq, const float* __restrict__ Wk,
    const float* __restrict__ Wv, uint16_t* __restrict__ dst) {
  int i = blockIdx.x * 256 + threadIdx.x;
  const int total = 2 * N4X + 3 * N4W;
  if (i >= total) return;
  const float* src;
  int j = i;
  if (j < N4X) {
    src = x1;
  } else if ((j -= N4X) < N4X) {
    src = x2;
  } else if ((j -= N4X) < N4W) {
    src = Wq;
  } else if ((j -= N4W) < N4W) {
    src = Wk;
  } else {
    j -= N4W;
    src = Wv;
  }
  float4 f = ((const float4*)src)[j];
  ushort4 o;
  o.x = f2bf(f.x); o.y = f2bf(f.y); o.z = f2bf(f.z); o.w = f2bf(f.w);
  ((ushort4*)dst)[i] = o;
}

// ---- proj v4 (operand-swapped): O[s][j] = relu(x[s,:].W[j,:] + b[j]).
// W-rows as the FIRST MFMA operand live in registers (64/wave = whole W[w]
// per block); x s-tiles stream through one 32KB LDS buffer. C layout puts
// j in the register dim (4 consecutive j/lane) -> packed 8B ushort4 stores;
// <=24 VMEM in flight per wave between drains (vmcnt queue is 63).
__global__ __launch_bounds__(256) void proj_kernel(
    const uint16_t* __restrict__ xb, const uint16_t* __restrict__ Wb,
    const float* __restrict__ bq, const float* __restrict__ bk,
    const float* __restrict__ bv, uint16_t* __restrict__ QKV) {
  __shared__ __align__(16) uint16_t Xsh[TS_JT * DIM];  // 32KB
  const int tid = threadIdx.x, lane = tid & 63, wave = tid >> 6;
  const int quad = lane >> 4, rlo = lane & 15;
  const int sb = blockIdx.x, z = blockIdx.y;
  const int w = z >> 1, p = z & 1;
  const float* bias = (w == 0) ? bq : (w == 1) ? bk : bv;
  const size_t T4 = (size_t)4 * S_LEN * DIM;

  // W fragments: this wave's 64 W-rows (output cols), full K=256, in regs.
  bf16x8 aW[4][8];
  {
    const uint16_t* Ab =
        Wb + w * (DIM * DIM) + (size_t)(wave * 64 + rlo) * DIM + quad * 8;
#pragma unroll
    for (int tm = 0; tm < 4; ++tm)
#pragma unroll
      for (int kc = 0; kc < 8; ++kc)
        aW[tm][kc] = *(const bf16x8*)(Ab + (size_t)tm * 16 * DIM + kc * 32);
  }
  // Bias for this lane's 16 j-columns (4 consecutive per tm), aligned float4.
  float4 bvec[4];
#pragma unroll
  for (int tm = 0; tm < 4; ++tm)
    bvec[tm] = *(const float4*)&bias[wave * 64 + tm * 16 + quad * 4];

  const uint16_t* Xbase = xb + p * T4 + (size_t)(sb * 128) * DIM;
  uint16_t* O = QKV + (size_t)(w * 2 + p) * T4;

  for (int jj = 0; jj < 2; ++jj) {
    stage64(Xbase + (size_t)jj * TS_JT * DIM, &Xsh[0], tid, wave);
    __builtin_amdgcn_s_waitcnt(0x0F70);  // vmcnt(0): DMA landed
    __syncthreads();
#pragma unroll
    for (int tn = 0; tn < 4; ++tn) {
      bf16x8 bfr[8];
      read_bfr(&Xsh[0], tn * 16 + rlo, quad, rlo, bfr);
      f32x4 acc[4];
      const f32x4 zero = {0.f, 0.f, 0.f, 0.f};
#pragma unroll
      for (int tm = 0; tm < 4; ++tm) acc[tm] = zero;
#pragma unroll
      for (int kc = 0; kc < 8; ++kc)
#pragma unroll
        for (int tm = 0; tm < 4; ++tm)
          acc[tm] = __builtin_amdgcn_mfma_f32_16x16x32_bf16(
              aW[tm][kc], bfr[kc], acc[tm], 0, 0, 0);
      const size_t srow = (size_t)(sb * 128 + jj * TS_JT + tn * 16 + rlo) * DIM;
#pragma unroll
      for (int tm = 0; tm < 4; ++tm) {
        float v0 = acc[tm][0] + bvec[tm].x;
        float v1 = acc[tm][1] + bvec[tm].y;
        float v2 = acc[tm][2] + bvec[tm].z;
        float v3 = acc[tm][3] + bvec[tm].w;
        ushort4 pk;
        pk.x = f2bf(v0 > 0.f ? v0 : 0.f);
        pk.y = f2bf(v1 > 0.f ? v1 : 0.f);
        pk.z = f2bf(v2 > 0.f ? v2 : 0.f);
        pk.w = f2bf(v3 > 0.f ? v3 : 0.f);
        *(ushort4*)(O + srow + wave * 64 + tm * 16 + quad * 4) = pk;
      }
    }
    __syncthreads();  // LDS reuse fence before next stage
  }
}

// ---- tanhsum: K-frags in regs, Q j-tiles through double-buffered LDS;
// ---- saturated tanh (dot>10 -> exactly 1.0f) skipped via wave-coherent test.
__global__ __launch_bounds__(256, 2) void tanhsum_kernel(
    const uint16_t* __restrict__ QKV, float* __restrict__ ssum) {
  __shared__ __align__(16) uint16_t Bsh[2][TS_JT * DIM];  // 2 x 32KB
  const int tid = threadIdx.x;
  const int lane = tid & 63, wave = tid >> 6;
  const int quad = lane >> 4, rlo = lane & 15;
  const int it = blockIdx.x, jcch = blockIdx.y, z = blockIdx.z;
  const int which = z >> 2, b = z & 3;
  const size_t T = (size_t)S_LEN * DIM;
  const uint16_t* Kp = QKV + (size_t)((2 + which) * 4 + b) * T;
  const uint16_t* Qp = QKV + (size_t)((which ^ 1) * 4 + b) * T;

  bf16x8 aA[4][8];
  {
    const uint16_t* Ab =
        Kp + (size_t)(it * TS_IBLK + wave * TS_WROWS + rlo) * DIM + quad * 8;
#pragma unroll
    for (int tm = 0; tm < 4; ++tm)
#pragma unroll
      for (int kc = 0; kc < 8; ++kc)
        aA[tm][kc] = *(const bf16x8*)(Ab + (size_t)tm * 16 * DIM + kc * 32);
  }

  float srun[4][4];
#pragma unroll
  for (int tm = 0; tm < 4; ++tm)
#pragma unroll
    for (int r = 0; r < 4; ++r) srun[tm][r] = 0.f;

  const uint16_t* Qbase = Qp + (size_t)(jcch * (S_LEN / TS_JCH)) * DIM;

  stage64(Qbase, &Bsh[0][0], tid, wave);
  __builtin_amdgcn_s_waitcnt(0x0F70);  // vmcnt(0)
  __syncthreads();

  for (int jj = 0; jj < TS_JITERS; ++jj) {
    const int buf = jj & 1;
    if (jj + 1 < TS_JITERS)
      stage64(Qbase + (size_t)(jj + 1) * TS_JT * DIM, &Bsh[buf ^ 1][0], tid, wave);
    const uint16_t* L = &Bsh[buf][0];
#pragma unroll
    for (int tn = 0; tn < 4; ++tn) {
      bf16x8 bfr[8];
      read_bfr(L, tn * 16 + rlo, quad, rlo, bfr);
      f32x4 acc[4];
      const f32x4 zero = {0.f, 0.f, 0.f, 0.f};
#pragma unroll
      for (int tm = 0; tm < 4; ++tm) acc[tm] = zero;
#pragma unroll
      for (int kc = 0; kc < 8; ++kc)
#pragma unroll
        for (int tm = 0; tm < 4; ++tm)
          acc[tm] = __builtin_amdgcn_mfma_f32_16x16x32_bf16(
              aA[tm][kc], bfr[kc], acc[tm], 0, 0, 0);
      // Saturation skip: tanh(x) == 1.0f exactly (fp32) for x > 10, and
      // tanh_fast returns exactly 1.0f there too -- bit-identical fast path.
      f32x4 m4 = fmin4(fmin4(acc[0], acc[1]), fmin4(acc[2], acc[3]));
      float mn = fminf(fminf(m4[0], m4[1]), fminf(m4[2], m4[3]));
      if (__all(mn > 10.0f)) {
#pragma unroll
        for (int tm = 0; tm < 4; ++tm)
#pragma unroll
          for (int r = 0; r < 4; ++r) srun[tm][r] += 1.0f;
      } else {
#pragma unroll
        for (int tm = 0; tm < 4; ++tm)
#pragma unroll
          for (int r = 0; r < 4; ++r) srun[tm][r] += tanh_fast(acc[tm][r]);
      }
    }
    __builtin_amdgcn_s_waitcnt(0x0F70);  // staging landed
    __syncthreads();
  }

  float* srow = ssum + (size_t)z * S_LEN + it * TS_IBLK + wave * TS_WROWS;
#pragma unroll
  for (int tm = 0; tm < 4; ++tm)
#pragma unroll
    for (int r = 0; r < 4; ++r) {
      float v = srun[tm][r];
      v += __shfl_xor(v, 1);
      v += __shfl_xor(v, 2);
      v += __shfl_xor(v, 4);
      v += __shfl_xor(v, 8);
      if (rlo == 0) atomicAdd(&srow[tm * 16 + quad * 4 + r], v);
    }
}

// ---------------- masked softmax over S, in place ----------------
__global__ __launch_bounds__(256) void softmax_kernel(
    float* __restrict__ ssum, const int* __restrict__ mask1,
    const int* __restrict__ mask2) {
  __shared__ float red[8];
  const int which = blockIdx.x >> 2, b = blockIdx.x & 3;
  const int* m = (which ? mask2 : mask1) + b * S_LEN;
  float* s = ssum + (size_t)(which * 4 + b) * S_LEN;
  const int tid = threadIdx.x;

  float lmax = -3.0e38f;
  for (int i = tid; i < S_LEN; i += 256)
    if (m[i] == 0) lmax = fmaxf(lmax, s[i]);
  for (int d = 32; d >= 1; d >>= 1) lmax = fmaxf(lmax, __shfl_xor(lmax, d));
  if ((tid & 63) == 0) red[tid >> 6] = lmax;
  __syncthreads();
  float gmax = fmaxf(fmaxf(red[0], red[1]), fmaxf(red[2], red[3]));

  float lsum = 0.f;
  for (int i = tid; i < S_LEN; i += 256) {
    float e = (m[i] == 0) ? __expf(s[i] - gmax) : 0.f;
    s[i] = e;
    lsum += e;
  }
  for (int d = 32; d >= 1; d >>= 1) lsum += __shfl_xor(lsum, d);
  if ((tid & 63) == 0) red[4 + (tid >> 6)] = lsum;
  __syncthreads();
  float inv = 1.0f / (red[4] + red[5] + red[6] + red[7]);
  for (int i = tid; i < S_LEN; i += 256) s[i] *= inv;
}

// -------- vec[which][b][d] = sum_s a[s]*V[s,d];  xmean accumulated too ------
__global__ __launch_bounds__(256) void vec_kernel(
    const float* __restrict__ a, const uint16_t* __restrict__ QKV,
    const uint16_t* __restrict__ xb, float* __restrict__ vec,
    float* __restrict__ xmean) {
  const int which = blockIdx.x >> 2, b = blockIdx.x & 3;
  const int chunk = blockIdx.y;  // 0..31 -> 128 rows each
  const int d = threadIdx.x;
  const size_t T = (size_t)S_LEN * DIM;
  const uint16_t* V = QKV + (size_t)((4 + which) * 4 + b) * T;
  const uint16_t* x = xb + (size_t)(which * 4 + b) * T;
  const float* aw = a + (size_t)(which * 4 + b) * S_LEN;

  float accv = 0.f, accx = 0.f;
  const int s0 = chunk * 128;
  for (int s = s0; s < s0 + 128; ++s) {
    accv += aw[s] * bf2f(V[(size_t)s * DIM + d]);
    accx += bf2f(x[(size_t)s * DIM + d]);
  }
  const int idx = (which * 4 + b) * DIM + d;
  atomicAdd(&vec[idx], accv);
  atomicAdd(&xmean[idx], accx * (1.0f / S_LEN));
}

// ---------------- layernorm(xmean + vec) ----------------
__global__ __launch_bounds__(256) void ln_kernel(
    const float* __restrict__ vec, const float* __restrict__ xmean,
    const float* __restrict__ gamma, const float* __restrict__ beta,
    float* __restrict__ out) {
  __shared__ float red[8];
  const int which = blockIdx.x >> 2, b = blockIdx.x & 3;
  const int d = threadIdx.x;
  const int idx = (which * 4 + b) * DIM + d;
  float y = xmean[idx] + vec[idx];

  float v = y;
  for (int m = 32; m >= 1; m >>= 1) v += __shfl_xor(v, m);
  if ((d & 63) == 0) red[d >> 6] = v;
  __syncthreads();
  float mu = (red[0] + red[1] + red[2] + red[3]) * (1.0f / DIM);
  __syncthreads();
  float c = y - mu;
  float v2 = c * c;
  for (int m = 32; m >= 1; m >>= 1) v2 += __shfl_xor(v2, m);
  if ((d & 63) == 0) red[4 + (d >> 6)] = v2;
  __syncthreads();
  float var = (red[4] + red[5] + red[6] + red[7]) * (1.0f / DIM);
  out[idx] = c * rsqrtf(var + 1e-5f) * gamma[d] + beta[d];
}

extern "C" void kernel_launch(void* const* d_in, const int* in_sizes, int n_in,
                              void* d_out, int out_size, void* d_ws,
                              size_t ws_size, hipStream_t stream) {
  (void)in_sizes; (void)n_in; (void)out_size; (void)ws_size;
  const float* x1 = (const float*)d_in[0];
  const float* x2 = (const float*)d_in[1];
  const int* mask1 = (const int*)d_in[2];
  const int* mask2 = (const int*)d_in[3];
  const float* Wq = (const float*)d_in[4];
  const float* bq = (const float*)d_in[5];
  const float* Wk = (const float*)d_in[6];
  const float* bk = (const float*)d_in[7];
  const float* Wv = (const float*)d_in[8];
  const float* bv = (const float*)d_in[9];
  const float* gamma = (const float*)d_in[10];
  const float* beta = (const float*)d_in[11];
  float* out = (float*)d_out;

  char* ws = (char*)d_ws;
  uint16_t* QKV = (uint16_t*)ws;              // 50,331,648 B  [w][p][b][s][d]
  uint16_t* xb = (uint16_t*)(ws + 50331648);  // 16,777,216 B  [p][b][s][d]
  uint16_t* Wb = (uint16_t*)(ws + 67108864);  //    393,216 B  [w][d][e]
  float* ssum = (float*)(ws + 67502080);      //    131,072 B  [which][b][s]
  float* vec = (float*)(ws + 67633152);       //      8,192 B
  float* xmean = (float*)(ws + 67641344);     //      8,192 B

  (void)hipMemsetAsync(ws + 67502080, 0, 131072 + 8192 + 8192, stream);

  const int total4 = 2 * N4X + 3 * N4W;
  cast_all_kernel<<<dim3((total4 + 255) / 256), 256, 0, stream>>>(
      x1, x2, Wq, Wk, Wv, xb);  // xb and Wb are contiguous in ws

  proj_kernel<<<dim3(128, 6), 256, 0, stream>>>(xb, Wb, bq, bk, bv, QKV);
  tanhsum_kernel<<<dim3(16, TS_JCH, 8), 256, 0, stream>>>(QKV, ssum);
  softmax_kernel<<<dim3(8), 256, 0, stream>>>(ssum, mask1, mask2);
  vec_kernel<<<dim3(8, 32), 256, 0, stream>>>(ssum, QKV, xb, vec, xmean);
  ln_kernel<<<dim3(8), 256, 0, stream>>>(vec, xmean, gamma, beta, out);
}